// Round 4
// baseline (1266.477 us; speedup 1.0000x reference)
//
#include <hip/hip_runtime.h>
#include <hip/hip_bf16.h>

#define D 128

// ---------------- setup kernels ----------------

__global__ void k_zero(int* __restrict__ p, int n) {
    int i = blockIdx.x * 256 + threadIdx.x;
    if (i < n) p[i] = 0;
}

__global__ void k_count(const int* __restrict__ dst, int* __restrict__ cnt, int e) {
    int i = blockIdx.x * 256 + threadIdx.x;
    if (i < e) atomicAdd(&cnt[dst[i]], 1);
}

__global__ void k_dinv(const int* __restrict__ cnt, float* __restrict__ dinv, int n) {
    int i = blockIdx.x * 256 + threadIdx.x;
    if (i < n) {
        float deg = (float)(cnt[i] + 2);   // +2 = improved self-loop weight
        dinv[i] = 1.0f / sqrtf(deg);
    }
}

// ---- hierarchical scan: A) per-block reduce, B) scan partials, C) rescan ----

__global__ __launch_bounds__(256) void k_scanA(const int* __restrict__ cnt,
                                               int* __restrict__ partials, int n) {
    __shared__ int s[256];
    int b = blockIdx.x, t = threadIdx.x;
    int i0 = b * 512 + t * 2;
    int v = 0;
    if (i0 < n) v += cnt[i0];
    if (i0 + 1 < n) v += cnt[i0 + 1];
    s[t] = v;
    __syncthreads();
    for (int off = 128; off > 0; off >>= 1) {
        if (t < off) s[t] += s[t + off];
        __syncthreads();
    }
    if (t == 0) partials[b] = s[0];
}

__global__ __launch_bounds__(512) void k_scanB(const int* __restrict__ partials,
                                               int* __restrict__ base,
                                               int* __restrict__ off_n, int nb) {
    __shared__ int s[512];
    int t = threadIdx.x;
    int v = (t < nb) ? partials[t] : 0;
    s[t] = v;
    __syncthreads();
    for (int off = 1; off < 512; off <<= 1) {
        int x = (t >= off) ? s[t - off] : 0;
        __syncthreads();
        s[t] += x;
        __syncthreads();
    }
    if (t < nb) base[t] = s[t] - v;          // exclusive
    if (t == nb - 1) off_n[0] = s[t];        // total = offsets[N]
}

__global__ __launch_bounds__(256) void k_scanC(const int* __restrict__ cnt,
                                               const int* __restrict__ base,
                                               int* __restrict__ offsets,
                                               int* __restrict__ cursor, int n) {
    __shared__ int s[256];
    int b = blockIdx.x, t = threadIdx.x;
    int i0 = b * 512 + t * 2;
    int v0 = (i0 < n) ? cnt[i0] : 0;
    int v1 = (i0 + 1 < n) ? cnt[i0 + 1] : 0;
    int sum = v0 + v1;
    s[t] = sum;
    __syncthreads();
    for (int off = 1; off < 256; off <<= 1) {
        int x = (t >= off) ? s[t - off] : 0;
        __syncthreads();
        s[t] += x;
        __syncthreads();
    }
    int excl = s[t] - sum + base[b];
    if (i0 < n) { offsets[i0] = excl; cursor[i0] = excl; }
    if (i0 + 1 < n) { offsets[i0 + 1] = excl + v0; cursor[i0 + 1] = excl + v0; }
}

// packed CSR entry: .x = src node, .y = float bits of norm weight
__global__ void k_fill(const int* __restrict__ src, const int* __restrict__ dst,
                       int* __restrict__ cursor, const float* __restrict__ dinv,
                       int2* __restrict__ csr, int e) {
    int i = blockIdx.x * 256 + threadIdx.x;
    if (i < e) {
        int s = src[i];
        int d = dst[i];
        int pos = atomicAdd(&cursor[d], 1);
        float w = dinv[s] * dinv[d];
        csr[pos] = make_int2(s, __float_as_int(w));
    }
}

// ---------------- matmul: O[r][c] = sum_k H[r][k] * W[k][c] ----------------
// 128x128 tile/block. Wave w computes rows {lane, lane+64} x cols [w*32, w*32+32).
// Per k: 2x ds_read_b32 (2-way bank alias = free) + 8x wave-uniform ds_read_b128
// (LDS same-address broadcast = free BW) feeding 64 FMAs -> FMA-bound.
__global__ __launch_bounds__(256) void k_matmul(const float* __restrict__ H,
                                                const float* __restrict__ W,
                                                float* __restrict__ O, int nrows) {
    __shared__ float Ws[32 * D];    // Ws[k][c]
    __shared__ float HsT[32 * D];   // HsT[k][r]
    const int t = threadIdx.x;
    const int wave = t >> 6;
    const int lane = t & 63;
    const int row0 = blockIdx.x * 128;

    float acc0[32], acc1[32];
#pragma unroll
    for (int j = 0; j < 32; j++) { acc0[j] = 0.f; acc1[j] = 0.f; }

    const int r_st = t & 127;
    const int kb = (t >> 7) * 16;   // 0 or 16

    for (int kc = 0; kc < D; kc += 32) {
        // stage W chunk: 4096 floats = 1024 float4
        {
            const float4* W4 = (const float4*)(W + kc * D);
            float4* Ws4 = (float4*)Ws;
#pragma unroll
            for (int it = 0; it < 4; it++) Ws4[t + it * 256] = W4[t + it * 256];
        }
        // stage transposed H chunk
        {
            int gr = row0 + r_st;
            float4 v0, v1, v2, v3;
            if (gr < nrows) {
                const float4* Hp = (const float4*)(H + (size_t)gr * D + kc + kb);
                v0 = Hp[0]; v1 = Hp[1]; v2 = Hp[2]; v3 = Hp[3];
            } else {
                v0 = v1 = v2 = v3 = make_float4(0.f, 0.f, 0.f, 0.f);
            }
            float vals[16];
            *(float4*)&vals[0]  = v0;
            *(float4*)&vals[4]  = v1;
            *(float4*)&vals[8]  = v2;
            *(float4*)&vals[12] = v3;
#pragma unroll
            for (int j = 0; j < 16; j++) HsT[(kb + j) * 128 + r_st] = vals[j];
        }
        __syncthreads();
#pragma unroll 4
        for (int k = 0; k < 32; k++) {
            float a0 = HsT[k * 128 + lane];
            float a1 = HsT[k * 128 + lane + 64];
            const float4* wr = (const float4*)&Ws[k * 128 + wave * 32];
            float4 b[8];
#pragma unroll
            for (int p = 0; p < 8; p++) b[p] = wr[p];
#pragma unroll
            for (int p = 0; p < 8; p++) {
                acc0[p * 4 + 0] += a0 * b[p].x; acc1[p * 4 + 0] += a1 * b[p].x;
                acc0[p * 4 + 1] += a0 * b[p].y; acc1[p * 4 + 1] += a1 * b[p].y;
                acc0[p * 4 + 2] += a0 * b[p].z; acc1[p * 4 + 2] += a1 * b[p].z;
                acc0[p * 4 + 3] += a0 * b[p].w; acc1[p * 4 + 3] += a1 * b[p].w;
            }
        }
        __syncthreads();
    }
    const int c0 = wave * 32;
    {
        int gr = row0 + lane;
        if (gr < nrows) {
            float4* Op = (float4*)(O + (size_t)gr * D + c0);
#pragma unroll
            for (int p = 0; p < 8; p++)
                Op[p] = make_float4(acc0[p * 4 + 0], acc0[p * 4 + 1],
                                    acc0[p * 4 + 2], acc0[p * 4 + 3]);
        }
        gr = row0 + lane + 64;
        if (gr < nrows) {
            float4* Op = (float4*)(O + (size_t)gr * D + c0);
#pragma unroll
            for (int p = 0; p < 8; p++)
                Op[p] = make_float4(acc1[p * 4 + 0], acc1[p * 4 + 1],
                                    acc1[p * 4 + 2], acc1[p * 4 + 3]);
        }
    }
}

// ---------------- gather ----------------
// one wave per node; half-wave per edge (32 lanes x float4 = 512B row);
// 8 edges/group -> 4 independent dual-row loads in flight (low VGPR, high occ).
__global__ __launch_bounds__(256) void k_gather(const float* __restrict__ T,
                                                const int2* __restrict__ csr,
                                                const int* __restrict__ offsets,
                                                const float* __restrict__ dinv,
                                                const float* __restrict__ bias,
                                                float* __restrict__ O, int n) {
    int node = blockIdx.x * 4 + (threadIdx.x >> 6);
    if (node >= n) return;
    int lane = threadIdx.x & 63;
    int half = lane >> 5;            // 0 or 1
    int c = (lane & 31) << 2;        // col base (float4)
    const float* Tc = T + c;

    float ax = 0.f, ay = 0.f, az = 0.f, aw = 0.f;
    if (half == 0) {
        float di = dinv[node];
        float sw = 2.0f * di * di;
        float4 v = *(const float4*)(Tc + (size_t)node * D);
        ax = sw * v.x; ay = sw * v.y; az = sw * v.z; aw = sw * v.w;
    }

    int e = offsets[node];
    const int e1 = offsets[node + 1];

    for (; e + 8 <= e1; e += 8) {
        int2 c0 = csr[e + half],     c1 = csr[e + 2 + half];
        int2 c2 = csr[e + 4 + half], c3 = csr[e + 6 + half];
        float4 v0 = *(const float4*)(Tc + (size_t)c0.x * D);
        float4 v1 = *(const float4*)(Tc + (size_t)c1.x * D);
        float4 v2 = *(const float4*)(Tc + (size_t)c2.x * D);
        float4 v3 = *(const float4*)(Tc + (size_t)c3.x * D);
        float w0 = __int_as_float(c0.y), w1 = __int_as_float(c1.y);
        float w2 = __int_as_float(c2.y), w3 = __int_as_float(c3.y);
        ax += w0 * v0.x; ay += w0 * v0.y; az += w0 * v0.z; aw += w0 * v0.w;
        ax += w1 * v1.x; ay += w1 * v1.y; az += w1 * v1.z; aw += w1 * v1.w;
        ax += w2 * v2.x; ay += w2 * v2.y; az += w2 * v2.z; aw += w2 * v2.w;
        ax += w3 * v3.x; ay += w3 * v3.y; az += w3 * v3.z; aw += w3 * v3.w;
    }
    for (; e + 2 <= e1; e += 2) {
        int2 c0 = csr[e + half];
        float4 v0 = *(const float4*)(Tc + (size_t)c0.x * D);
        float w0 = __int_as_float(c0.y);
        ax += w0 * v0.x; ay += w0 * v0.y; az += w0 * v0.z; aw += w0 * v0.w;
    }
    if (e < e1 && half == 0) {
        int2 c0 = csr[e];
        float4 v0 = *(const float4*)(Tc + (size_t)c0.x * D);
        float w0 = __int_as_float(c0.y);
        ax += w0 * v0.x; ay += w0 * v0.y; az += w0 * v0.z; aw += w0 * v0.w;
    }

    ax += __shfl_xor(ax, 32, 64);
    ay += __shfl_xor(ay, 32, 64);
    az += __shfl_xor(az, 32, 64);
    aw += __shfl_xor(aw, 32, 64);

    if (half == 0) {
        const float4 b4 = *(const float4*)(bias + c);
        float4 r = make_float4(ax + b4.x, ay + b4.y, az + b4.z, aw + b4.w);
        *(float4*)(O + (size_t)node * D + c) = r;
    }
}

// ---------------- launch ----------------

extern "C" void kernel_launch(void* const* d_in, const int* in_sizes, int n_in,
                              void* d_out, int out_size, void* d_ws, size_t ws_size,
                              hipStream_t stream) {
    const float* x  = (const float*)d_in[0];
    const int*   ei = (const int*)d_in[1];
    const float* W1 = (const float*)d_in[2];
    const float* b1 = (const float*)d_in[3];
    const float* W2 = (const float*)d_in[4];
    const float* b2 = (const float*)d_in[5];
    const int N = in_sizes[0] / D;
    const int E = in_sizes[1] / 2;
    float* out = (float*)d_out;

    char* ws = (char*)d_ws;
    size_t woff = 0;
    auto alloc = [&](size_t bytes) -> void* {
        void* p = ws + woff;
        woff = (woff + bytes + 15) & ~(size_t)15;
        return p;
    };
    float* T        = (float*)alloc((size_t)N * D * sizeof(float));
    int*   cnt      = (int*)  alloc((size_t)N * sizeof(int));
    int*   offsets  = (int*)  alloc((size_t)(N + 1) * sizeof(int));
    int*   cursor   = (int*)  alloc((size_t)N * sizeof(int));
    float* dinv     = (float*)alloc((size_t)N * sizeof(float));
    int2*  csr      = (int2*) alloc((size_t)E * sizeof(int2));
    int*   partials = (int*)  alloc(1024 * sizeof(int));
    int*   base     = (int*)  alloc(1024 * sizeof(int));
    (void)ws_size; (void)n_in; (void)out_size;

    const int* e_src = ei;
    const int* e_dst = ei + E;
    const int NB = (N + 511) / 512;   // 196 <= 512

    k_zero<<<(N + 255) / 256, 256, 0, stream>>>(cnt, N);
    k_count<<<(E + 255) / 256, 256, 0, stream>>>(e_dst, cnt, E);
    k_dinv<<<(N + 255) / 256, 256, 0, stream>>>(cnt, dinv, N);
    k_scanA<<<NB, 256, 0, stream>>>(cnt, partials, N);
    k_scanB<<<1, 512, 0, stream>>>(partials, base, offsets + N, NB);
    k_scanC<<<NB, 256, 0, stream>>>(cnt, base, offsets, cursor, N);
    k_fill<<<(E + 255) / 256, 256, 0, stream>>>(e_src, e_dst, cursor, dinv, csr, E);

    const float* h = x;
    for (int l = 0; l < 5; l++) {
        const float* W = l ? W2 : W1;
        const float* b = l ? b2 : b1;
        k_matmul<<<(N + 127) / 128, 256, 0, stream>>>(h, W, T, N);
        k_gather<<<(N + 3) / 4, 256, 0, stream>>>(T, csr, offsets, dinv, b, out, N);
        h = out;
    }
}

// Round 5
// 1161.930 us; speedup vs baseline: 1.0900x; 1.0900x over previous
//
#include <hip/hip_runtime.h>
#include <hip/hip_bf16.h>

#define D 128
#define APITCH 136   // 128 + 8 bf16 pad: breaks 16-way b128 bank conflict

typedef float f32x4 __attribute__((ext_vector_type(4)));
typedef short bf16x8 __attribute__((ext_vector_type(8)));

__device__ inline unsigned short f2bf(float x) {
    unsigned u = __float_as_uint(x);
    u += 0x7fff + ((u >> 16) & 1);     // RNE
    return (unsigned short)(u >> 16);
}
__device__ inline float bf2f(unsigned short s) {
    return __uint_as_float(((unsigned)s) << 16);
}

// ---------------- setup kernels ----------------

__global__ void k_zero(int* __restrict__ p, int n) {
    int i = blockIdx.x * 256 + threadIdx.x;
    if (i < n) p[i] = 0;
}

__global__ void k_count(const int* __restrict__ dst, int* __restrict__ cnt, int e) {
    int i = blockIdx.x * 256 + threadIdx.x;
    if (i < e) atomicAdd(&cnt[dst[i]], 1);
}

__global__ void k_dinv(const int* __restrict__ cnt, float* __restrict__ dinv, int n) {
    int i = blockIdx.x * 256 + threadIdx.x;
    if (i < n) {
        float deg = (float)(cnt[i] + 2);   // +2 = improved self-loop weight
        dinv[i] = 1.0f / sqrtf(deg);
    }
}

// split W[k][n] fp32 -> transposed Wh/Wl[n][k] bf16 hi/lo
__global__ void k_wsplit(const float* __restrict__ W,
                         unsigned short* __restrict__ Wh,
                         unsigned short* __restrict__ Wl) {
    int t = blockIdx.x * 256 + threadIdx.x;
    if (t < D * D) {
        int k = t >> 7, n = t & 127;
        float x = W[t];
        unsigned short h = f2bf(x);
        unsigned short l = f2bf(x - bf2f(h));
        Wh[n * D + k] = h;
        Wl[n * D + k] = l;
    }
}

// ---- hierarchical scan: A) per-block reduce, B) scan partials, C) rescan ----

__global__ __launch_bounds__(256) void k_scanA(const int* __restrict__ cnt,
                                               int* __restrict__ partials, int n) {
    __shared__ int s[256];
    int b = blockIdx.x, t = threadIdx.x;
    int i0 = b * 512 + t * 2;
    int v = 0;
    if (i0 < n) v += cnt[i0];
    if (i0 + 1 < n) v += cnt[i0 + 1];
    s[t] = v;
    __syncthreads();
    for (int off = 128; off > 0; off >>= 1) {
        if (t < off) s[t] += s[t + off];
        __syncthreads();
    }
    if (t == 0) partials[b] = s[0];
}

__global__ __launch_bounds__(512) void k_scanB(const int* __restrict__ partials,
                                               int* __restrict__ base,
                                               int* __restrict__ off_n, int nb) {
    __shared__ int s[512];
    int t = threadIdx.x;
    int v = (t < nb) ? partials[t] : 0;
    s[t] = v;
    __syncthreads();
    for (int off = 1; off < 512; off <<= 1) {
        int x = (t >= off) ? s[t - off] : 0;
        __syncthreads();
        s[t] += x;
        __syncthreads();
    }
    if (t < nb) base[t] = s[t] - v;          // exclusive
    if (t == nb - 1) off_n[0] = s[t];        // total = offsets[N]
}

__global__ __launch_bounds__(256) void k_scanC(const int* __restrict__ cnt,
                                               const int* __restrict__ base,
                                               int* __restrict__ offsets,
                                               int* __restrict__ cursor, int n) {
    __shared__ int s[256];
    int b = blockIdx.x, t = threadIdx.x;
    int i0 = b * 512 + t * 2;
    int v0 = (i0 < n) ? cnt[i0] : 0;
    int v1 = (i0 + 1 < n) ? cnt[i0 + 1] : 0;
    int sum = v0 + v1;
    s[t] = sum;
    __syncthreads();
    for (int off = 1; off < 256; off <<= 1) {
        int x = (t >= off) ? s[t - off] : 0;
        __syncthreads();
        s[t] += x;
        __syncthreads();
    }
    int excl = s[t] - sum + base[b];
    if (i0 < n) { offsets[i0] = excl; cursor[i0] = excl; }
    if (i0 + 1 < n) { offsets[i0 + 1] = excl + v0; cursor[i0 + 1] = excl + v0; }
}

// packed CSR entry: .x = src node, .y = float bits of norm weight
__global__ void k_fill(const int* __restrict__ src, const int* __restrict__ dst,
                       int* __restrict__ cursor, const float* __restrict__ dinv,
                       int2* __restrict__ csr, int e) {
    int i = blockIdx.x * 256 + threadIdx.x;
    if (i < e) {
        int s = src[i];
        int d = dst[i];
        int pos = atomicAdd(&cursor[d], 1);
        float w = dinv[s] * dinv[d];
        csr[pos] = make_int2(s, __float_as_int(w));
    }
}

// ---------------- matmul: O = H @ W via split-bf16 MFMA ----------------
// block = 256 thr (4 waves), 64 rows x 128 cols. K=128 staged once in LDS.
// wave w: rows [w*16,w*16+16), 8 col-tiles of 16x16x32 MFMA, 3 mfma per tile
// (hi*hi + lo*hi + hi*lo). B-frags read straight from global (L2-hot 64KB).
__global__ __launch_bounds__(256) void k_matmul(const float* __restrict__ H,
                                                const unsigned short* __restrict__ Wh,
                                                const unsigned short* __restrict__ Wl,
                                                float* __restrict__ O, int nrows) {
    __shared__ unsigned short Ahi[64 * APITCH];
    __shared__ unsigned short Alo[64 * APITCH];
    const int t = threadIdx.x;
    const int wave = t >> 6, lane = t & 63;
    const int ln = lane & 15, quad = lane >> 4;
    const int r0 = blockIdx.x * 64;

    // stage + hi/lo split H rows [r0, r0+64)
#pragma unroll
    for (int j = 0; j < 8; j++) {
        int i = t + j * 256;          // float4 index, 2048 total
        int row = i >> 5;             // 32 float4 per row
        int c4 = (i & 31) << 2;       // float col
        float4 v = make_float4(0.f, 0.f, 0.f, 0.f);
        int gr = r0 + row;
        if (gr < nrows) v = *(const float4*)(H + (size_t)gr * D + c4);
        unsigned short hx = f2bf(v.x), hy = f2bf(v.y), hz = f2bf(v.z), hw = f2bf(v.w);
        unsigned short lx = f2bf(v.x - bf2f(hx)), ly = f2bf(v.y - bf2f(hy));
        unsigned short lz = f2bf(v.z - bf2f(hz)), lw = f2bf(v.w - bf2f(hw));
        *(uint2*)&Ahi[row * APITCH + c4] =
            make_uint2((unsigned)hx | ((unsigned)hy << 16),
                       (unsigned)hz | ((unsigned)hw << 16));
        *(uint2*)&Alo[row * APITCH + c4] =
            make_uint2((unsigned)lx | ((unsigned)ly << 16),
                       (unsigned)lz | ((unsigned)lw << 16));
    }
    __syncthreads();

    f32x4 acc[8];
#pragma unroll
    for (int i = 0; i < 8; i++) acc[i] = (f32x4){0.f, 0.f, 0.f, 0.f};

    const int mrow = wave * 16 + ln;
#pragma unroll
    for (int c = 0; c < 4; c++) {
        // A-frag layout (m120-verified): A[m=lane&15][k=quad*8+j]
        bf16x8 a_hi = *(const bf16x8*)&Ahi[mrow * APITCH + c * 32 + quad * 8];
        bf16x8 a_lo = *(const bf16x8*)&Alo[mrow * APITCH + c * 32 + quad * 8];
#pragma unroll
        for (int nt = 0; nt < 8; nt++) {
            // B-frag: Bt[n=lane&15][k=quad*8+j], 16B aligned, one 64B line/n/chunk
            int boff = (nt * 16 + ln) * D + c * 32 + quad * 8;
            bf16x8 b_hi = *(const bf16x8*)(Wh + boff);
            bf16x8 b_lo = *(const bf16x8*)(Wl + boff);
            acc[nt] = __builtin_amdgcn_mfma_f32_16x16x32_bf16(a_hi, b_hi, acc[nt], 0, 0, 0);
            acc[nt] = __builtin_amdgcn_mfma_f32_16x16x32_bf16(a_lo, b_hi, acc[nt], 0, 0, 0);
            acc[nt] = __builtin_amdgcn_mfma_f32_16x16x32_bf16(a_hi, b_lo, acc[nt], 0, 0, 0);
        }
    }

    // C/D layout (m89/m91-verified): col = lane&15, row = quad*4 + reg
    const int orow = r0 + wave * 16 + quad * 4;
#pragma unroll
    for (int nt = 0; nt < 8; nt++) {
#pragma unroll
        for (int r = 0; r < 4; r++) {
            int gr = orow + r;
            if (gr < nrows) O[(size_t)gr * D + nt * 16 + ln] = acc[nt][r];
        }
    }
}

// ---------------- gather ----------------
// one wave per node; half-wave per edge (32 lanes x float4 = 512B row);
// 8 edges/group -> 4 independent dual-row loads in flight.
__global__ __launch_bounds__(256) void k_gather(const float* __restrict__ T,
                                                const int2* __restrict__ csr,
                                                const int* __restrict__ offsets,
                                                const float* __restrict__ dinv,
                                                const float* __restrict__ bias,
                                                float* __restrict__ O, int n) {
    int node = blockIdx.x * 4 + (threadIdx.x >> 6);
    if (node >= n) return;
    int lane = threadIdx.x & 63;
    int half = lane >> 5;            // 0 or 1
    int c = (lane & 31) << 2;        // col base (float4)
    const float* Tc = T + c;

    float ax = 0.f, ay = 0.f, az = 0.f, aw = 0.f;
    if (half == 0) {
        float di = dinv[node];
        float sw = 2.0f * di * di;
        float4 v = *(const float4*)(Tc + (size_t)node * D);
        ax = sw * v.x; ay = sw * v.y; az = sw * v.z; aw = sw * v.w;
    }

    int e = offsets[node];
    const int e1 = offsets[node + 1];

    for (; e + 8 <= e1; e += 8) {
        int2 c0 = csr[e + half],     c1 = csr[e + 2 + half];
        int2 c2 = csr[e + 4 + half], c3 = csr[e + 6 + half];
        float4 v0 = *(const float4*)(Tc + (size_t)c0.x * D);
        float4 v1 = *(const float4*)(Tc + (size_t)c1.x * D);
        float4 v2 = *(const float4*)(Tc + (size_t)c2.x * D);
        float4 v3 = *(const float4*)(Tc + (size_t)c3.x * D);
        float w0 = __int_as_float(c0.y), w1 = __int_as_float(c1.y);
        float w2 = __int_as_float(c2.y), w3 = __int_as_float(c3.y);
        ax += w0 * v0.x; ay += w0 * v0.y; az += w0 * v0.z; aw += w0 * v0.w;
        ax += w1 * v1.x; ay += w1 * v1.y; az += w1 * v1.z; aw += w1 * v1.w;
        ax += w2 * v2.x; ay += w2 * v2.y; az += w2 * v2.z; aw += w2 * v2.w;
        ax += w3 * v3.x; ay += w3 * v3.y; az += w3 * v3.z; aw += w3 * v3.w;
    }
    for (; e + 2 <= e1; e += 2) {
        int2 c0 = csr[e + half];
        float4 v0 = *(const float4*)(Tc + (size_t)c0.x * D);
        float w0 = __int_as_float(c0.y);
        ax += w0 * v0.x; ay += w0 * v0.y; az += w0 * v0.z; aw += w0 * v0.w;
    }
    if (e < e1 && half == 0) {
        int2 c0 = csr[e];
        float4 v0 = *(const float4*)(Tc + (size_t)c0.x * D);
        float w0 = __int_as_float(c0.y);
        ax += w0 * v0.x; ay += w0 * v0.y; az += w0 * v0.z; aw += w0 * v0.w;
    }

    ax += __shfl_xor(ax, 32, 64);
    ay += __shfl_xor(ay, 32, 64);
    az += __shfl_xor(az, 32, 64);
    aw += __shfl_xor(aw, 32, 64);

    if (half == 0) {
        const float4 b4 = *(const float4*)(bias + c);
        float4 r = make_float4(ax + b4.x, ay + b4.y, az + b4.z, aw + b4.w);
        *(float4*)(O + (size_t)node * D + c) = r;
    }
}

// ---------------- launch ----------------

extern "C" void kernel_launch(void* const* d_in, const int* in_sizes, int n_in,
                              void* d_out, int out_size, void* d_ws, size_t ws_size,
                              hipStream_t stream) {
    const float* x  = (const float*)d_in[0];
    const int*   ei = (const int*)d_in[1];
    const float* W1 = (const float*)d_in[2];
    const float* b1 = (const float*)d_in[3];
    const float* W2 = (const float*)d_in[4];
    const float* b2 = (const float*)d_in[5];
    const int N = in_sizes[0] / D;
    const int E = in_sizes[1] / 2;
    float* out = (float*)d_out;

    char* ws = (char*)d_ws;
    size_t woff = 0;
    auto alloc = [&](size_t bytes) -> void* {
        void* p = ws + woff;
        woff = (woff + bytes + 15) & ~(size_t)15;
        return p;
    };
    float* T        = (float*)alloc((size_t)N * D * sizeof(float));
    int*   cnt      = (int*)  alloc((size_t)N * sizeof(int));
    int*   offsets  = (int*)  alloc((size_t)(N + 1) * sizeof(int));
    int*   cursor   = (int*)  alloc((size_t)N * sizeof(int));
    float* dinv     = (float*)alloc((size_t)N * sizeof(float));
    int2*  csr      = (int2*) alloc((size_t)E * sizeof(int2));
    int*   partials = (int*)  alloc(1024 * sizeof(int));
    int*   base     = (int*)  alloc(1024 * sizeof(int));
    unsigned short* W1h = (unsigned short*)alloc(D * D * sizeof(unsigned short));
    unsigned short* W1l = (unsigned short*)alloc(D * D * sizeof(unsigned short));
    unsigned short* W2h = (unsigned short*)alloc(D * D * sizeof(unsigned short));
    unsigned short* W2l = (unsigned short*)alloc(D * D * sizeof(unsigned short));
    (void)ws_size; (void)n_in; (void)out_size;

    const int* e_src = ei;
    const int* e_dst = ei + E;
    const int NB = (N + 511) / 512;   // 196 <= 512

    k_zero<<<(N + 255) / 256, 256, 0, stream>>>(cnt, N);
    k_count<<<(E + 255) / 256, 256, 0, stream>>>(e_dst, cnt, E);
    k_dinv<<<(N + 255) / 256, 256, 0, stream>>>(cnt, dinv, N);
    k_scanA<<<NB, 256, 0, stream>>>(cnt, partials, N);
    k_scanB<<<1, 512, 0, stream>>>(partials, base, offsets + N, NB);
    k_scanC<<<NB, 256, 0, stream>>>(cnt, base, offsets, cursor, N);
    k_fill<<<(E + 255) / 256, 256, 0, stream>>>(e_src, e_dst, cursor, dinv, csr, E);
    k_wsplit<<<64, 256, 0, stream>>>(W1, W1h, W1l);
    k_wsplit<<<64, 256, 0, stream>>>(W2, W2h, W2l);

    const float* h = x;
    for (int l = 0; l < 5; l++) {
        const unsigned short* Wh = l ? W2h : W1h;
        const unsigned short* Wl = l ? W2l : W1l;
        const float* b = l ? b2 : b1;
        k_matmul<<<(N + 63) / 64, 256, 0, stream>>>(h, Wh, Wl, T, N);
        k_gather<<<(N + 3) / 4, 256, 0, stream>>>(T, csr, offsets, dinv, b, out, N);
        h = out;
    }
}